// Round 1
// baseline (574.795 us; speedup 1.0000x reference)
//
#include <hip/hip_runtime.h>
#include <hip/hip_bf16.h>
#include <stdint.h>

#define B_  2
#define S_  4096
#define D_  1024
#define FF_ 4096
#define E_  8
#define C_  1024

typedef unsigned short u16;
typedef unsigned int   u32;
typedef float f32x4  __attribute__((ext_vector_type(4)));
typedef short bf16x8 __attribute__((ext_vector_type(8)));
typedef u16   u16x8  __attribute__((ext_vector_type(8)));

static __device__ __forceinline__ u16 f2bf(float f) {
    union { float f; u32 u; } v; v.f = f;
    u32 u = v.u;
    u32 r = (u + 0x7FFFu + ((u >> 16) & 1u)) >> 16;  // RNE; inputs are finite
    return (u16)r;
}

static __device__ __forceinline__ void gload_lds16(const u16* g, u16* l) {
    __builtin_amdgcn_global_load_lds(
        (const __attribute__((address_space(1))) u32*)g,
        (__attribute__((address_space(3))) u32*)l, 16, 0, 0);
}

// ---------------- conversion: hidden fp32 -> bf16 (no transpose) ----------------
__global__ __launch_bounds__(256) void cvt_hidden(const float* __restrict__ src,
                                                  u16* __restrict__ dst, int n8) {
    int i = blockIdx.x * 256 + threadIdx.x;
    if (i >= n8) return;
    const float4* s = (const float4*)src + (size_t)i * 2;
    float4 a = s[0], b = s[1];
    u16x8 o;
    o[0] = f2bf(a.x); o[1] = f2bf(a.y); o[2] = f2bf(a.z); o[3] = f2bf(a.w);
    o[4] = f2bf(b.x); o[5] = f2bf(b.y); o[6] = f2bf(b.z); o[7] = f2bf(b.w);
    *((u16x8*)dst + i) = o;
}

// ---------------- transpose + convert: [K][N] fp32 -> [N][K] bf16, per expert ----------------
__global__ __launch_bounds__(256) void transpose_cvt(const float* __restrict__ src,
                                                     u16* __restrict__ dst, int K, int N) {
    __shared__ float tile[32][33];
    size_t mat = (size_t)blockIdx.z * K * N;
    int n0 = blockIdx.x * 32, k0 = blockIdx.y * 32;
    int tx = threadIdx.x & 31, ty = threadIdx.x >> 5;   // 32 x 8
#pragma unroll
    for (int i = 0; i < 32; i += 8)
        tile[ty + i][tx] = src[mat + (size_t)(k0 + ty + i) * N + n0 + tx];
    __syncthreads();
#pragma unroll
    for (int i = 0; i < 32; i += 8)
        dst[mat + (size_t)(n0 + ty + i) * K + k0 + tx] = f2bf(tile[tx][ty + i]);
}

// ---------------- router: logits (fp64 accum), argmax, max softmax prob ----------------
__global__ __launch_bounds__(256) void router_kernel(const float* __restrict__ hidden,
                                                     const float* __restrict__ gate_w,
                                                     float* __restrict__ logits_out,
                                                     int* __restrict__ sel,
                                                     float* __restrict__ maxp) {
    __shared__ float gw[D_ * E_];   // 32 KB
    for (int i = threadIdx.x; i < D_ * E_ / 4; i += 256)
        ((float4*)gw)[i] = ((const float4*)gate_w)[i];
    __syncthreads();

    int wave = threadIdx.x >> 6, lane = threadIdx.x & 63;
    int tok = blockIdx.x * 4 + wave;              // [0, B*S)
    const float* hrow = hidden + (size_t)tok * D_;

    double acc[8] = {0, 0, 0, 0, 0, 0, 0, 0};
#pragma unroll 4
    for (int i = 0; i < D_ / 64; i++) {
        int d = i * 64 + lane;
        float h = hrow[d];
        const float4* g4 = (const float4*)(gw + d * 8);
        float4 g0 = g4[0], g1 = g4[1];
        acc[0] += (double)h * g0.x; acc[1] += (double)h * g0.y;
        acc[2] += (double)h * g0.z; acc[3] += (double)h * g0.w;
        acc[4] += (double)h * g1.x; acc[5] += (double)h * g1.y;
        acc[6] += (double)h * g1.z; acc[7] += (double)h * g1.w;
    }
#pragma unroll
    for (int off = 32; off > 0; off >>= 1)
#pragma unroll
        for (int e = 0; e < 8; e++)
            acc[e] += __shfl_xor(acc[e], off);

    float l[8];
#pragma unroll
    for (int e = 0; e < 8; e++) l[e] = (float)acc[e];
    if (lane < 8) logits_out[(size_t)tok * 8 + lane] = l[lane];

    int am = 0; float mx = l[0];
#pragma unroll
    for (int e = 1; e < 8; e++) if (l[e] > mx) { mx = l[e]; am = e; }   // first max, like argmax
    float sum = 0.f;
#pragma unroll
    for (int e = 0; e < 8; e++) sum += expf(l[e] - mx);
    if (lane == 0) { sel[tok] = am; maxp[tok] = 1.0f / sum; }
}

// ---------------- routing scan: per-(batch,expert) rank via wave ballots ----------------
__global__ void scan_kernel(const int* __restrict__ sel, int* __restrict__ pos,
                            int* __restrict__ slot_token, int* __restrict__ counts) {
    int wave = threadIdx.x >> 6, lane = threadIdx.x & 63;
    int b = wave;                                  // blockDim = 128 -> waves 0,1 = batches
    int carry[8] = {0, 0, 0, 0, 0, 0, 0, 0};
    unsigned long long below = (lane == 0) ? 0ull : ((~0ull) >> (64 - lane));
    for (int s0 = 0; s0 < S_; s0 += 64) {
        int s = s0 + lane;
        int e = sel[b * S_ + s];
        int p = 0;
#pragma unroll
        for (int ex = 0; ex < 8; ex++) {
            unsigned long long m = __ballot(e == ex);
            if (e == ex) p = carry[ex] + (int)__popcll(m & below);
            carry[ex] += (int)__popcll(m);
        }
        pos[b * S_ + s] = p;
        if (p < C_) slot_token[(b * E_ + e) * C_ + p] = s;
    }
    if (lane < 8) {
        int c = carry[lane];
        counts[b * E_ + lane] = c < C_ ? c : C_;
    }
}

// ---------------- GEMM1: h = silu(x@w1) * (x@w3), gathered A, compacted slots ----------------
// grid: x = FF/64, y = C/128, z = B*E.  block = 256 (4 waves, 2x2), tile 128x64 per panel, BK=64.
__global__ __launch_bounds__(256) void gemm1_kernel(const u16* __restrict__ x,     // [B*S, D] bf16
                                                    const u16* __restrict__ w1t,   // [E, FF, D] bf16
                                                    const u16* __restrict__ w3t,   // [E, FF, D] bf16
                                                    const int* __restrict__ slot_token,
                                                    const int* __restrict__ counts,
                                                    u16* __restrict__ hbuf) {      // [B*E, C, FF] bf16
    int z = blockIdx.z;
    int cnt = counts[z];
    int c0 = blockIdx.y * 128;
    if (c0 >= cnt) return;
    int n0 = blockIdx.x * 64;
    int b = z >> 3, e = z & 7;

    __shared__ u16 As[128 * 64];
    __shared__ u16 B1s[64 * 64];
    __shared__ u16 B3s[64 * 64];

    int tid = threadIdx.x, wave = tid >> 6, lane = tid & 63;
    int wr = wave >> 1, wc = wave & 1;

    // per-lane pre-swizzled global row bases (constant over K loop)
    const u16* a_src[4];
#pragma unroll
    for (int i = 0; i < 4; i++) {
        int chunk = wave * 4 + i;
        int row = chunk * 8 + (lane >> 3);
        int slot = c0 + row;
        int s = (slot < cnt) ? slot_token[z * C_ + slot] : 0;
        int srcslot = (lane & 7) ^ (row & 7);
        a_src[i] = x + ((size_t)(b * S_ + s)) * D_ + srcslot * 8;
    }
    const u16 *b1_src[2], *b3_src[2];
#pragma unroll
    for (int i = 0; i < 2; i++) {
        int chunk = wave * 2 + i;
        int row = chunk * 8 + (lane >> 3);
        int srcslot = (lane & 7) ^ (row & 7);
        size_t off = ((size_t)e * FF_ + n0 + row) * D_ + srcslot * 8;
        b1_src[i] = w1t + off;
        b3_src[i] = w3t + off;
    }

    f32x4 acc1[4][2] = {};
    f32x4 acc3[4][2] = {};

    for (int k0 = 0; k0 < D_; k0 += 64) {
#pragma unroll
        for (int i = 0; i < 4; i++)
            gload_lds16(a_src[i] + k0, As + (wave * 4 + i) * 512);
#pragma unroll
        for (int i = 0; i < 2; i++) {
            gload_lds16(b1_src[i] + k0, B1s + (wave * 2 + i) * 512);
            gload_lds16(b3_src[i] + k0, B3s + (wave * 2 + i) * 512);
        }
        __syncthreads();
#pragma unroll
        for (int kk = 0; kk < 2; kk++) {
            bf16x8 af[4];
#pragma unroll
            for (int fm = 0; fm < 4; fm++) {
                int row = wr * 64 + fm * 16 + (lane & 15);
                int sl = (kk * 4 + (lane >> 4)) ^ (row & 7);
                af[fm] = *(const bf16x8*)(As + row * 64 + sl * 8);
            }
            bf16x8 b1f[2], b3f[2];
#pragma unroll
            for (int fn = 0; fn < 2; fn++) {
                int nl = wc * 32 + fn * 16 + (lane & 15);
                int sl = (kk * 4 + (lane >> 4)) ^ (nl & 7);
                b1f[fn] = *(const bf16x8*)(B1s + nl * 64 + sl * 8);
                b3f[fn] = *(const bf16x8*)(B3s + nl * 64 + sl * 8);
            }
#pragma unroll
            for (int fm = 0; fm < 4; fm++)
#pragma unroll
                for (int fn = 0; fn < 2; fn++) {
                    acc1[fm][fn] = __builtin_amdgcn_mfma_f32_16x16x32_bf16(af[fm], b1f[fn], acc1[fm][fn], 0, 0, 0);
                    acc3[fm][fn] = __builtin_amdgcn_mfma_f32_16x16x32_bf16(af[fm], b3f[fn], acc3[fm][fn], 0, 0, 0);
                }
        }
        __syncthreads();
    }

#pragma unroll
    for (int fm = 0; fm < 4; fm++) {
        int rbase = c0 + wr * 64 + fm * 16 + ((lane >> 4) << 2);
#pragma unroll
        for (int fn = 0; fn < 2; fn++) {
            int col = n0 + wc * 32 + fn * 16 + (lane & 15);
#pragma unroll
            for (int r = 0; r < 4; r++) {
                int slot = rbase + r;
                if (slot < cnt) {
                    float g = acc1[fm][fn][r];
                    float u = acc3[fm][fn][r];
                    float h = (g / (1.f + __expf(-g))) * u;
                    hbuf[((size_t)z * C_ + slot) * FF_ + col] = f2bf(h);
                }
            }
        }
    }
}

// ---------------- GEMM2: out[token] = maxp * (h @ w2), scatter epilogue ----------------
// grid: x = D/128, y = C/128, z = B*E.  block = 256 (4 waves, 2x2), tile 128x128, BK=64.
__global__ __launch_bounds__(256) void gemm2_kernel(const u16* __restrict__ hbuf,  // [B*E, C, FF]
                                                    const u16* __restrict__ w2t,   // [E, D, FF]
                                                    const int* __restrict__ slot_token,
                                                    const int* __restrict__ counts,
                                                    const float* __restrict__ maxp,
                                                    float* __restrict__ out) {     // [B*S, D]
    int z = blockIdx.z;
    int cnt = counts[z];
    int c0 = blockIdx.y * 128;
    if (c0 >= cnt) return;
    int n0 = blockIdx.x * 128;
    int b = z >> 3, e = z & 7;

    __shared__ u16 As[128 * 64];
    __shared__ u16 Bs[128 * 64];

    int tid = threadIdx.x, wave = tid >> 6, lane = tid & 63;
    int wr = wave >> 1, wc = wave & 1;

    const u16 *a_src[4], *b_src[4];
#pragma unroll
    for (int i = 0; i < 4; i++) {
        int chunk = wave * 4 + i;
        int row = chunk * 8 + (lane >> 3);
        int srcslot = (lane & 7) ^ (row & 7);
        a_src[i] = hbuf + ((size_t)z * C_ + c0 + row) * FF_ + srcslot * 8;
        b_src[i] = w2t + ((size_t)e * D_ + n0 + row) * FF_ + srcslot * 8;
    }

    f32x4 acc[4][4] = {};

    for (int k0 = 0; k0 < FF_; k0 += 64) {
#pragma unroll
        for (int i = 0; i < 4; i++) {
            gload_lds16(a_src[i] + k0, As + (wave * 4 + i) * 512);
            gload_lds16(b_src[i] + k0, Bs + (wave * 4 + i) * 512);
        }
        __syncthreads();
#pragma unroll
        for (int kk = 0; kk < 2; kk++) {
            bf16x8 af[4], bfv[4];
#pragma unroll
            for (int fm = 0; fm < 4; fm++) {
                int row = wr * 64 + fm * 16 + (lane & 15);
                int sl = (kk * 4 + (lane >> 4)) ^ (row & 7);
                af[fm] = *(const bf16x8*)(As + row * 64 + sl * 8);
            }
#pragma unroll
            for (int fn = 0; fn < 4; fn++) {
                int nl = wc * 64 + fn * 16 + (lane & 15);
                int sl = (kk * 4 + (lane >> 4)) ^ (nl & 7);
                bfv[fn] = *(const bf16x8*)(Bs + nl * 64 + sl * 8);
            }
#pragma unroll
            for (int fm = 0; fm < 4; fm++)
#pragma unroll
                for (int fn = 0; fn < 4; fn++)
                    acc[fm][fn] = __builtin_amdgcn_mfma_f32_16x16x32_bf16(af[fm], bfv[fn], acc[fm][fn], 0, 0, 0);
        }
        __syncthreads();
    }

#pragma unroll
    for (int fm = 0; fm < 4; fm++) {
        int rbase = c0 + wr * 64 + fm * 16 + ((lane >> 4) << 2);
#pragma unroll
        for (int r = 0; r < 4; r++) {
            int slot = rbase + r;
            if (slot < cnt) {
                int s = slot_token[z * C_ + slot];
                float sc = maxp[b * S_ + s];
                float* orow = out + ((size_t)b * S_ + s) * D_;
#pragma unroll
                for (int fn = 0; fn < 4; fn++) {
                    int col = n0 + wc * 64 + fn * 16 + (lane & 15);
                    orow[col] = sc * acc[fm][fn][r];
                }
            }
        }
    }
}

// ---------------- dropped tokens keep hidden (rare; usually no-op) ----------------
__global__ __launch_bounds__(256) void combine_dropped(const float* __restrict__ hidden,
                                                       const int* __restrict__ pos,
                                                       const float* __restrict__ maxp,
                                                       float* __restrict__ out) {
    int t = blockIdx.x;
    if (pos[t] < C_) return;
    float sc = maxp[t];
    const float* src = hidden + (size_t)t * D_;
    float* dst = out + (size_t)t * D_;
    for (int d = threadIdx.x; d < D_; d += 256) dst[d] = sc * src[d];
}

extern "C" void kernel_launch(void* const* d_in, const int* in_sizes, int n_in,
                              void* d_out, int out_size, void* d_ws, size_t ws_size,
                              hipStream_t stream) {
    const float* hidden = (const float*)d_in[0];
    const float* gate_w = (const float*)d_in[1];
    const float* w1     = (const float*)d_in[2];
    const float* w2     = (const float*)d_in[3];
    const float* w3     = (const float*)d_in[4];

    float* out        = (float*)d_out;
    float* logits_out = out + (size_t)B_ * S_ * D_;

    char* ws = (char*)d_ws;
    u16* hidden_bf = (u16*)ws;            ws += (size_t)B_ * S_ * D_ * 2;
    u16* w1t       = (u16*)ws;            ws += (size_t)E_ * D_ * FF_ * 2;
    u16* w3t       = (u16*)ws;            ws += (size_t)E_ * D_ * FF_ * 2;
    u16* w2t       = (u16*)ws;            ws += (size_t)E_ * D_ * FF_ * 2;
    u16* hbuf      = (u16*)ws;            ws += (size_t)B_ * E_ * C_ * FF_ * 2;
    int*   sel        = (int*)ws;         ws += (size_t)B_ * S_ * 4;
    int*   pos        = (int*)ws;         ws += (size_t)B_ * S_ * 4;
    float* maxp       = (float*)ws;       ws += (size_t)B_ * S_ * 4;
    int*   slot_token = (int*)ws;         ws += (size_t)B_ * E_ * C_ * 4;
    int*   counts     = (int*)ws;         ws += (size_t)B_ * E_ * 4;

    cvt_hidden<<<(B_ * S_ * D_ / 8 + 255) / 256, 256, 0, stream>>>(hidden, hidden_bf, B_ * S_ * D_ / 8);
    transpose_cvt<<<dim3(FF_ / 32, D_ / 32, E_), 256, 0, stream>>>(w1, w1t, D_, FF_);
    transpose_cvt<<<dim3(FF_ / 32, D_ / 32, E_), 256, 0, stream>>>(w3, w3t, D_, FF_);
    transpose_cvt<<<dim3(D_ / 32, FF_ / 32, E_), 256, 0, stream>>>(w2, w2t, FF_, D_);

    router_kernel<<<B_ * S_ / 4, 256, 0, stream>>>(hidden, gate_w, logits_out, sel, maxp);
    scan_kernel<<<1, 128, 0, stream>>>(sel, pos, slot_token, counts);

    gemm1_kernel<<<dim3(FF_ / 64, C_ / 128, B_ * E_), 256, 0, stream>>>(hidden_bf, w1t, w3t, slot_token, counts, hbuf);
    gemm2_kernel<<<dim3(D_ / 128, C_ / 128, B_ * E_), 256, 0, stream>>>(hbuf, w2t, slot_token, counts, maxp, out);
    combine_dropped<<<B_ * S_, 256, 0, stream>>>(hidden, pos, maxp, out);
}